// Round 1
// baseline (1318.759 us; speedup 1.0000x reference)
//
#include <hip/hip_runtime.h>

#define B_DIM 4
#define S_DIM 4096
#define D_DIM 256
#define L_DIM 8921

typedef _Float16 f16x8 __attribute__((ext_vector_type(8)));
typedef _Float16 f16x4 __attribute__((ext_vector_type(4)));
typedef float    f32x4 __attribute__((ext_vector_type(4)));

// ---------------------------------------------------------------------------
// K0a: split x (fp32) -> x_hi, x_lo (f16), elementwise. a = hi + lo to ~2^-22.
// ---------------------------------------------------------------------------
__global__ __launch_bounds__(256) void k_split_x(const float* __restrict__ x,
                                                 _Float16* __restrict__ xh,
                                                 _Float16* __restrict__ xl) {
  const size_t i = ((size_t)blockIdx.x * 256 + threadIdx.x) * 4;
  float4 v = *(const float4*)(x + i);
  f16x4 h, l;
  h.x = (_Float16)v.x; l.x = (_Float16)(v.x - (float)h.x);
  h.y = (_Float16)v.y; l.y = (_Float16)(v.y - (float)h.y);
  h.z = (_Float16)v.z; l.z = (_Float16)(v.z - (float)h.z);
  h.w = (_Float16)v.w; l.w = (_Float16)(v.w - (float)h.w);
  *(f16x4*)(xh + i) = h;
  *(f16x4*)(xl + i) = l;
}

// ---------------------------------------------------------------------------
// K0b: split U (fp32) -> U_hi, U_lo (f16)
// ---------------------------------------------------------------------------
__global__ __launch_bounds__(256) void k_split_u(const float* __restrict__ U,
                                                 _Float16* __restrict__ uh,
                                                 _Float16* __restrict__ ul) {
  const size_t i = ((size_t)blockIdx.x * 256 + threadIdx.x) * 4;
  if (i >= (size_t)L_DIM * D_DIM) return;
  float4 v = *(const float4*)(U + i);
  f16x4 h, l;
  h.x = (_Float16)v.x; l.x = (_Float16)(v.x - (float)h.x);
  h.y = (_Float16)v.y; l.y = (_Float16)(v.y - (float)h.y);
  h.z = (_Float16)v.z; l.z = (_Float16)(v.z - (float)h.z);
  h.w = (_Float16)v.w; l.w = (_Float16)(v.w - (float)h.w);
  *(f16x4*)(uh + i) = h;
  *(f16x4*)(ul + i) = l;
}

// ---------------------------------------------------------------------------
// K0c: xT_hi[b][d][s] = f16(x[b][s][d])  (tiled 32x32 transpose via LDS)
// grid: (S/32, D/32, B), block 256
// ---------------------------------------------------------------------------
__global__ __launch_bounds__(256) void k_transpose(const float* __restrict__ x,
                                                   _Float16* __restrict__ xT) {
  __shared__ _Float16 t[32][33];
  const int s0 = blockIdx.x * 32, d0 = blockIdx.y * 32, b = blockIdx.z;
  const float* xb = x + (size_t)b * S_DIM * D_DIM;
  const int r = threadIdx.x >> 5, c = threadIdx.x & 31;
#pragma unroll
  for (int p = 0; p < 4; ++p) {
    const int row = r + p * 8;  // s index within tile
    t[row][c] = (_Float16)xb[(size_t)(s0 + row) * D_DIM + d0 + c];
  }
  __syncthreads();
  _Float16* xtb = xT + (size_t)b * D_DIM * S_DIM;
#pragma unroll
  for (int p = 0; p < 4; ++p) {
    const int row = r + p * 8;  // d index within tile
    xtb[(size_t)(d0 + row) * S_DIM + s0 + c] = t[c][row];
  }
}

// ---------------------------------------------------------------------------
// K1: scores[b][l][s] = sum_d U[l,d] x[b,s,d]   (raw fp32, into alpha region)
// NT GEMM, 128x128 tile, BK=32, split-f16 3-product for fp32-level accuracy.
// grid: (S/128, ceil(L/128), B), block 256 (4 waves, 2x2, each 64x64)
// ---------------------------------------------------------------------------
__global__ __launch_bounds__(256) void k_scores(const _Float16* __restrict__ Uh,
                                                const _Float16* __restrict__ Ul,
                                                const _Float16* __restrict__ Xh,
                                                const _Float16* __restrict__ Xl,
                                                float* __restrict__ scores) {
  const int s0 = blockIdx.x * 128;
  const int l0 = blockIdx.y * 128;
  const int b  = blockIdx.z;

  __shared__ _Float16 Ah[128 * 32], Al[128 * 32], Bh[128 * 32], Bl[128 * 32];

  const int tid = threadIdx.x;
  const int wave = tid >> 6, lane = tid & 63;
  const int wm = wave & 1, wn = wave >> 1;

  const _Float16* Xbh = Xh + (size_t)b * S_DIM * D_DIM;
  const _Float16* Xbl = Xl + (size_t)b * S_DIM * D_DIM;

  f32x4 acc[4][4] = {};

  const int srow = tid >> 2;          // 0..63, two passes cover 128 rows
  const int soff = (tid & 3) * 8;     // 8 f16 = 16B per thread

  for (int k0 = 0; k0 < D_DIM; k0 += 32) {
#pragma unroll
    for (int p = 0; p < 2; ++p) {
      const int row = srow + p * 64;
      const int l = l0 + row;
      uint4 vh = make_uint4(0, 0, 0, 0), vl = make_uint4(0, 0, 0, 0);
      if (l < L_DIM) {
        vh = *(const uint4*)(Uh + (size_t)l * D_DIM + k0 + soff);
        vl = *(const uint4*)(Ul + (size_t)l * D_DIM + k0 + soff);
      }
      *(uint4*)(Ah + row * 32 + soff) = vh;
      *(uint4*)(Al + row * 32 + soff) = vl;
      const int s = s0 + row;
      *(uint4*)(Bh + row * 32 + soff) =
          *(const uint4*)(Xbh + (size_t)s * D_DIM + k0 + soff);
      *(uint4*)(Bl + row * 32 + soff) =
          *(const uint4*)(Xbl + (size_t)s * D_DIM + k0 + soff);
    }
    __syncthreads();

    const int frow = lane & 15;
    const int fk = (lane >> 4) * 8;
    f16x8 ah[4], al[4], bh[4], bl[4];
#pragma unroll
    for (int i = 0; i < 4; ++i) {
      ah[i] = *(const f16x8*)(Ah + (wm * 64 + i * 16 + frow) * 32 + fk);
      al[i] = *(const f16x8*)(Al + (wm * 64 + i * 16 + frow) * 32 + fk);
      bh[i] = *(const f16x8*)(Bh + (wn * 64 + i * 16 + frow) * 32 + fk);
      bl[i] = *(const f16x8*)(Bl + (wn * 64 + i * 16 + frow) * 32 + fk);
    }
#pragma unroll
    for (int i = 0; i < 4; ++i)
#pragma unroll
      for (int j = 0; j < 4; ++j) {
        acc[i][j] = __builtin_amdgcn_mfma_f32_16x16x32_f16(ah[i], bh[j], acc[i][j], 0, 0, 0);
        acc[i][j] = __builtin_amdgcn_mfma_f32_16x16x32_f16(ah[i], bl[j], acc[i][j], 0, 0, 0);
        acc[i][j] = __builtin_amdgcn_mfma_f32_16x16x32_f16(al[i], bh[j], acc[i][j], 0, 0, 0);
      }
    __syncthreads();
  }

  float* sc = scores + (size_t)b * L_DIM * S_DIM;
#pragma unroll
  for (int i = 0; i < 4; ++i)
#pragma unroll
    for (int j = 0; j < 4; ++j) {
      const int col = s0 + wn * 64 + j * 16 + (lane & 15);
#pragma unroll
      for (int r = 0; r < 4; ++r) {
        const int row = l0 + wm * 64 + i * 16 + (lane >> 4) * 4 + r;
        if (row < L_DIM) sc[(size_t)row * S_DIM + col] = acc[i][j][r];
      }
    }
}

// ---------------------------------------------------------------------------
// K2: per-row softmax stats: stats[b][l] = {rowmax, 1/sum(exp(s-m))}
// grid: (L, B), block 256; each block one row of 4096 floats.
// ---------------------------------------------------------------------------
__global__ __launch_bounds__(256) void k_stats(const float* __restrict__ scores,
                                               float* __restrict__ stats) {
  const int l = blockIdx.x;
  const int b = blockIdx.y;
  const float* row = scores + ((size_t)b * L_DIM + l) * S_DIM;
  const int tid = threadIdx.x;
  const float4* rp = (const float4*)(row + tid * 16);
  const float4 a0 = rp[0], a1 = rp[1], a2 = rp[2], a3 = rp[3];

  float m = fmaxf(fmaxf(fmaxf(a0.x, a0.y), fmaxf(a0.z, a0.w)),
                  fmaxf(fmaxf(fmaxf(a1.x, a1.y), fmaxf(a1.z, a1.w)),
                        fmaxf(fmaxf(fmaxf(a2.x, a2.y), fmaxf(a2.z, a2.w)),
                              fmaxf(fmaxf(a3.x, a3.y), fmaxf(a3.z, a3.w)))));
#pragma unroll
  for (int off = 32; off >= 1; off >>= 1) m = fmaxf(m, __shfl_xor(m, off));

  __shared__ float redm[4], reds[4];
  const int wave = tid >> 6, lane = tid & 63;
  if (lane == 0) redm[wave] = m;
  __syncthreads();
  m = fmaxf(fmaxf(redm[0], redm[1]), fmaxf(redm[2], redm[3]));

  float s = __expf(a0.x - m) + __expf(a0.y - m) + __expf(a0.z - m) + __expf(a0.w - m)
          + __expf(a1.x - m) + __expf(a1.y - m) + __expf(a1.z - m) + __expf(a1.w - m)
          + __expf(a2.x - m) + __expf(a2.y - m) + __expf(a2.z - m) + __expf(a2.w - m)
          + __expf(a3.x - m) + __expf(a3.y - m) + __expf(a3.z - m) + __expf(a3.w - m);
#pragma unroll
  for (int off = 32; off >= 1; off >>= 1) s += __shfl_xor(s, off);
  if (lane == 0) reds[wave] = s;
  __syncthreads();
  if (tid == 0) {
    const float tot = reds[0] + reds[1] + reds[2] + reds[3];
    float* st = stats + ((size_t)b * L_DIM + l) * 2;
    st[0] = m;
    st[1] = 1.0f / tot;
  }
}

// ---------------------------------------------------------------------------
// K3: alpha = softmax(scores) written in-place (fp32); out = alpha @ x via
// f16 MFMA. Each block owns a 64-row l-tile x full D=256, loops K=S in 32s.
// grid: (ceil(L/64), B), block 256 (4 waves along D, each 64x64).
// ---------------------------------------------------------------------------
__global__ __launch_bounds__(256) void k_out(const _Float16* __restrict__ XT,
                                             const float* __restrict__ stats,
                                             float* __restrict__ alpha,
                                             float* __restrict__ out) {
  const int l0 = blockIdx.x * 64;
  const int b  = blockIdx.y;
  const int tid = threadIdx.x;
  const int wave = tid >> 6, lane = tid & 63;

  __shared__ _Float16 Aa[64 * 32];
  __shared__ _Float16 Bb[256 * 32];
  __shared__ float sm[64], sr[64];

  if (tid < 64) {
    const int l = l0 + tid;
    float m = 0.f, r = 0.f;
    if (l < L_DIM) {
      const float* st = stats + ((size_t)b * L_DIM + l) * 2;
      m = st[0];
      r = st[1];
    }
    sm[tid] = m;
    sr[tid] = r;
  }
  __syncthreads();

  f32x4 acc[4][4] = {};
  float* al_base = alpha + (size_t)b * L_DIM * S_DIM;
  const _Float16* xt = XT + (size_t)b * D_DIM * S_DIM;

  const int arow = tid >> 3, aoff = (tid & 7) * 4;  // scores: 32 rows/pass
  const int brow = tid >> 2, boff = (tid & 3) * 8;  // xT: 64 rows/pass

  for (int s0 = 0; s0 < S_DIM; s0 += 32) {
#pragma unroll
    for (int p = 0; p < 2; ++p) {
      const int row = arow + p * 32;
      const int l = l0 + row;
      float4 v = make_float4(0.f, 0.f, 0.f, 0.f);
      if (l < L_DIM) {
        float* ap = al_base + (size_t)l * S_DIM + s0 + aoff;
        v = *(const float4*)ap;
        const float m = sm[row], r = sr[row];
        v.x = __expf(v.x - m) * r;
        v.y = __expf(v.y - m) * r;
        v.z = __expf(v.z - m) * r;
        v.w = __expf(v.w - m) * r;
        *(float4*)ap = v;  // final alpha, fp32-accurate, in-place
      }
      f16x4 pk;
      pk.x = (_Float16)v.x;
      pk.y = (_Float16)v.y;
      pk.z = (_Float16)v.z;
      pk.w = (_Float16)v.w;
      *(f16x4*)(Aa + row * 32 + aoff) = pk;
    }
#pragma unroll
    for (int p = 0; p < 4; ++p) {
      const int row = brow + p * 64;
      *(uint4*)(Bb + row * 32 + boff) =
          *(const uint4*)(xt + (size_t)row * S_DIM + s0 + boff);
    }
    __syncthreads();

    const int frow = lane & 15;
    const int fk = (lane >> 4) * 8;
    f16x8 af[4], bf[4];
#pragma unroll
    for (int i = 0; i < 4; ++i) {
      af[i] = *(const f16x8*)(Aa + (i * 16 + frow) * 32 + fk);
      bf[i] = *(const f16x8*)(Bb + (wave * 64 + i * 16 + frow) * 32 + fk);
    }
#pragma unroll
    for (int i = 0; i < 4; ++i)
#pragma unroll
      for (int j = 0; j < 4; ++j)
        acc[i][j] = __builtin_amdgcn_mfma_f32_16x16x32_f16(af[i], bf[j], acc[i][j], 0, 0, 0);
    __syncthreads();
  }

  float* ob = out + (size_t)b * L_DIM * D_DIM;
#pragma unroll
  for (int i = 0; i < 4; ++i)
#pragma unroll
    for (int j = 0; j < 4; ++j) {
      const int d = wave * 64 + j * 16 + (lane & 15);
#pragma unroll
      for (int r = 0; r < 4; ++r) {
        const int l = l0 + i * 16 + (lane >> 4) * 4 + r;
        if (l < L_DIM) ob[(size_t)l * D_DIM + d] = acc[i][j][r];
      }
    }
}

// ---------------------------------------------------------------------------
extern "C" void kernel_launch(void* const* d_in, const int* in_sizes, int n_in,
                              void* d_out, int out_size, void* d_ws, size_t ws_size,
                              hipStream_t stream) {
  const float* x = (const float*)d_in[0];
  const float* U = (const float*)d_in[1];
  float* out   = (float*)d_out;
  float* alpha = out + (size_t)B_DIM * L_DIM * D_DIM;  // raw scores, then alpha

  const size_t NX = (size_t)B_DIM * S_DIM * D_DIM;  // 4,194,304
  const size_t NU = (size_t)L_DIM * D_DIM;          // 2,283,776

  // workspace layout (~34 MB): x_hi, x_lo, xT_hi, U_hi, U_lo, stats
  char* w = (char*)d_ws;
  _Float16* xh = (_Float16*)w; w += NX * 2;
  _Float16* xl = (_Float16*)w; w += NX * 2;
  _Float16* xT = (_Float16*)w; w += NX * 2;
  _Float16* uh = (_Float16*)w; w += NU * 2;
  _Float16* ul = (_Float16*)w; w += NU * 2;
  float* stats = (float*)w;

  k_split_x<<<dim3((unsigned)(NX / 1024)), 256, 0, stream>>>(x, xh, xl);
  k_split_u<<<dim3((unsigned)((NU / 4 + 255) / 256)), 256, 0, stream>>>(U, uh, ul);
  k_transpose<<<dim3(S_DIM / 32, D_DIM / 32, B_DIM), 256, 0, stream>>>(x, xT);
  k_scores<<<dim3(S_DIM / 128, (L_DIM + 127) / 128, B_DIM), 256, 0, stream>>>(
      uh, ul, xh, xl, alpha);
  k_stats<<<dim3(L_DIM, B_DIM), 256, 0, stream>>>(alpha, stats);
  k_out<<<dim3((L_DIM + 63) / 64, B_DIM), 256, 0, stream>>>(xT, stats, alpha, out);
}